// Round 3
// baseline (287.863 us; speedup 1.0000x reference)
//
#include <hip/hip_runtime.h>
#include <stdint.h>

#define D_K 512
#define C_CLS 85742
#define N_TILES 670            // ceil(85742/128)
#define N_PART (N_TILES * 2)

using bf16x8 = __attribute__((ext_vector_type(8))) short;
using f32x4  = __attribute__((ext_vector_type(4))) float;

__device__ __forceinline__ unsigned short f2bf(float f) {
  unsigned int u = __builtin_bit_cast(unsigned int, f);
  u += 0x7FFFu + ((u >> 16) & 1u);          // round-to-nearest-even
  return (unsigned short)(u >> 16);
}
__device__ __forceinline__ float bf2f(unsigned short h) {
  return __builtin_bit_cast(float, ((unsigned int)h) << 16);
}
__device__ __forceinline__ float sq8(const float4& a, const float4& b) {
  return a.x*a.x + a.y*a.y + a.z*a.z + a.w*a.w +
         b.x*b.x + b.y*b.y + b.z*b.z + b.w*b.w;
}
__device__ __forceinline__ void pack8(const float4& a, const float4& b, unsigned short* h) {
  h[0]=f2bf(a.x); h[1]=f2bf(a.y); h[2]=f2bf(a.z); h[3]=f2bf(a.w);
  h[4]=f2bf(b.x); h[5]=f2bf(b.y); h[6]=f2bf(b.z); h[7]=f2bf(b.w);
}

// ---------------- Pass A: normalize x -> bf16 xn, save ||x|| ----------------
__global__ __launch_bounds__(256) void k_xnorm(const float* __restrict__ X,
                                               unsigned short* __restrict__ XN,
                                               float* __restrict__ FN) {
  int row  = blockIdx.x * 4 + (threadIdx.x >> 6);
  int lane = threadIdx.x & 63;
  const float4* px = (const float4*)(X + (size_t)row * D_K + lane * 8);
  float4 u = px[0], v = px[1];
  float nsq = sq8(u, v);
#pragma unroll
  for (int m = 1; m <= 32; m <<= 1) nsq += __shfl_xor(nsq, m);
  float nrm = sqrtf(nsq);
  float inv = 1.0f / fmaxf(nrm, 1e-12f);
  float4 a = make_float4(u.x*inv, u.y*inv, u.z*inv, u.w*inv);
  float4 b = make_float4(v.x*inv, v.y*inv, v.z*inv, v.w*inv);
  alignas(16) unsigned short h[8];
  pack8(a, b, h);
  *(bf16x8*)(XN + (size_t)row * D_K + lane * 8) = *(const bf16x8*)h;
  if (lane == 0) FN[row] = nrm;
}

// ---- Pass C: 128x128 bf16 MFMA GEMM. 512 threads (8 waves, wave-tile 32x64),
// ---- BK=64, LDS double-buffered, ONE __syncthreads per K-step (T3 minimum
// ---- 2-phase: STAGE next -> compute current -> convert B -> barrier).
// ---- XOR chunk-swizzle (c ^ (row&7)) on A (pre-swizzled glds source) and B
// ---- (swizzled ds_write) kills the 16-way row-stride-128B bank conflict.
// ---- Fused per-row ||w||^2; epilogue emits per-(row,64col) (max,sumexp).
__global__ __launch_bounds__(512, 4) void k_gemm_lse(const float* __restrict__ W,
                                                     const unsigned short* __restrict__ XN,
                                                     const float* __restrict__ FN,
                                                     float2* __restrict__ PART) {
  __shared__ alignas(16) unsigned short As[2][8192];   // [buf][128 rows x 64 cols]
  __shared__ alignas(16) unsigned short Bs[2][8192];
  __shared__ float nsqS[128];
  __shared__ float fnS[128];

  int bid = blockIdx.x;
  // bijective XCD chunking: 2680 = 8*335; 4 m-blocks of an n-tile stay on one XCD
  int wg    = (bid & 7) * 335 + (bid >> 3);
  int ntile = wg >> 2, mtile = wg & 3;
  int m0 = mtile * 128, n0 = ntile * 128;

  int t    = threadIdx.x;
  int lane = t & 63, wid = t >> 6;          // 8 waves
  int wm = wid >> 1, wn = wid & 1;          // 4 x 2 wave grid, wave-tile 32x64
  int s = lane & 15, g = lane >> 4;

  // ---- B staging: thread t owns row rB = t>>2, f32 cols (t&3)*16..+15 ----
  int rB = t >> 2;
  int gr = n0 + rB; if (gr > C_CLS - 1) gr = C_CLS - 1;
  const float* pB = W + (size_t)gr * D_K + (t & 3) * 16;
  // swizzled store chunk indices (chunk = 16B = 8 bf16; 8 chunks/row)
  int sw0 = ((2 * (t & 3))     ^ (rB & 7)) * 8 + rB * 64;
  int sw1 = ((2 * (t & 3) + 1) ^ (rB & 7)) * 8 + rB * 64;

  // ---- A staging via global_load_lds, pre-swizzled global source ----
  // inst j (j=0,1): LDS ushort idx = wid*1024 + j*512 + lane*8 (linear dest)
  //  -> row r = wid*16 + j*8 + (lane>>3), stored chunk = lane&7
  //  -> logical chunk c = (lane&7) ^ ((lane>>3)&7)
  int rA = wid * 16 + (lane >> 3);
  int cA = (lane & 7) ^ ((lane >> 3) & 7);
  const unsigned short* gA0 = XN + (size_t)(m0 + rA) * D_K + cA * 8;

  f32x4 acc[2][4] = {};
  float nsq = 0.f;
  float4 rb0, rb1, rb2, rb3;

#define GLDS(srcp, dstp) __builtin_amdgcn_global_load_lds( \
    (const __attribute__((address_space(1))) unsigned int*)(srcp), \
    (__attribute__((address_space(3))) unsigned int*)(dstp), 16, 0, 0)

#define STAGE_A(b, kk) do { \
    GLDS(gA0 + (size_t)(kk) * 64,            &As[b][wid * 1024]); \
    GLDS(gA0 + 8 * D_K + (size_t)(kk) * 64,  &As[b][wid * 1024 + 512]); \
  } while (0)

#define PREF_B(kk) do { \
    const float* q_ = pB + (size_t)(kk) * 64; \
    rb0 = *(const float4*)q_;       rb1 = *(const float4*)(q_ + 4); \
    rb2 = *(const float4*)(q_ + 8); rb3 = *(const float4*)(q_ + 12); \
  } while (0)

#define CONV_B(b) do { \
    nsq += sq8(rb0, rb1) + sq8(rb2, rb3); \
    alignas(16) unsigned short h0_[8], h1_[8]; \
    pack8(rb0, rb1, h0_); pack8(rb2, rb3, h1_); \
    *(bf16x8*)(&Bs[b][sw0]) = *(const bf16x8*)h0_; \
    *(bf16x8*)(&Bs[b][sw1]) = *(const bf16x8*)h1_; \
  } while (0)

  // fragment read: logical chunk (kh*4+g) of row, stored at chunk^(row&7)
#define FRAGS_MFMA(b) do { \
    bf16x8 af[2][2], bfr[4][2]; \
    _Pragma("unroll") for (int mf = 0; mf < 2; ++mf) { \
      int m_ = wm * 32 + mf * 16 + s; \
      _Pragma("unroll") for (int kh = 0; kh < 2; ++kh) \
        af[mf][kh] = *(const bf16x8*)(&As[b][m_ * 64 + ((kh * 4 + g) ^ (m_ & 7)) * 8]); \
    } \
    _Pragma("unroll") for (int nf = 0; nf < 4; ++nf) { \
      int r_ = wn * 64 + nf * 16 + s; \
      _Pragma("unroll") for (int kh = 0; kh < 2; ++kh) \
        bfr[nf][kh] = *(const bf16x8*)(&Bs[b][r_ * 64 + ((kh * 4 + g) ^ (r_ & 7)) * 8]); \
    } \
    _Pragma("unroll") for (int mf = 0; mf < 2; ++mf) \
      _Pragma("unroll") for (int nf = 0; nf < 4; ++nf) \
        _Pragma("unroll") for (int kh = 0; kh < 2; ++kh) \
          acc[mf][nf] = __builtin_amdgcn_mfma_f32_16x16x32_bf16(af[mf][kh], bfr[nf][kh], acc[mf][nf], 0, 0, 0); \
  } while (0)

  // ---- prologue: tile 0 into buf0 ----
  PREF_B(0);
  STAGE_A(0, 0);
  if (t < 128) fnS[t] = FN[m0 + t];
  __syncthreads();              // drains B(0) reg-loads + A(0) glds
  CONV_B(0);
  __syncthreads();              // buf0 B visible

  // ---- main loop: 8 K-steps, one barrier each ----
  for (int kt = 0; kt < 8; ++kt) {
    int cur = kt & 1;
    if (kt < 7) {
      STAGE_A(cur ^ 1, kt + 1); // async glds, covered by MFMA phase below
      PREF_B(kt + 1);           // reg loads, covered by MFMA phase below
    }
    FRAGS_MFMA(cur);
    if (kt < 7) {
      CONV_B(cur ^ 1);          // B regs have landed under MFMA
      __syncthreads();          // drains A-glds (covered); publishes buf^1
    }
  }

  // finish per-row ||w||^2 (4 col-chunk owners: t, t^1, t^2)
  nsq += __shfl_xor(nsq, 1); nsq += __shfl_xor(nsq, 2);
  if ((t & 3) == 0) nsqS[rB] = nsq;
  __syncthreads();

  float rinv[4]; int cvalid[4];
#pragma unroll
  for (int nf = 0; nf < 4; ++nf) {
    int cl = wn * 64 + nf * 16 + s;
    cvalid[nf] = (n0 + cl) < C_CLS;
    rinv[nf] = 1.0f / fmaxf(sqrtf(nsqS[cl]), 1e-12f);
  }
  const float NEG_INF = -__builtin_inff();
#pragma unroll
  for (int mf = 0; mf < 2; ++mf) {
#pragma unroll
    for (int q = 0; q < 4; ++q) {
      int rl = wm * 32 + mf * 16 + g * 4 + q;     // D row = (lane>>4)*4+reg
      float fr = fnS[rl];
      float z[4]; float mx = NEG_INF;
#pragma unroll
      for (int nf = 0; nf < 4; ++nf) {
        float cc = acc[mf][nf][q] * rinv[nf];
        cc = fminf(fmaxf(cc, -1.0f), 1.0f);
        z[nf] = cvalid[nf] ? cc * fr : NEG_INF;
        mx = fmaxf(mx, z[nf]);
      }
#pragma unroll
      for (int d = 1; d <= 8; d <<= 1) mx = fmaxf(mx, __shfl_xor(mx, d));
      float se = 0.f;
#pragma unroll
      for (int nf = 0; nf < 4; ++nf) se += __expf(z[nf] - mx);  // exp(-inf)=0
#pragma unroll
      for (int d = 1; d <= 8; d <<= 1) se += __shfl_xor(se, d);
      if (s == mf * 4 + q)
        PART[(size_t)(m0 + rl) * N_PART + (ntile * 2 + wn)] = make_float2(mx, se);
    }
  }
}

// ------- Pass D: per-row target logit (unmodified + margin-modified) --------
__global__ __launch_bounds__(64) void k_target(const float* __restrict__ W,
                                               const unsigned short* __restrict__ XN,
                                               const float* __restrict__ FN,
                                               const int* __restrict__ LBL,
                                               float2* __restrict__ ZT) {
  int row = blockIdx.x;
  int lane = threadIdx.x;
  int lab = LBL[row];
  const float* pw = W + (size_t)lab * D_K + lane * 8;
  const unsigned short* px = XN + (size_t)row * D_K + lane * 8;
  float dot = 0.f, nsq = 0.f;
#pragma unroll
  for (int j = 0; j < 8; ++j) {
    float w = pw[j];
    nsq += w * w;
    dot += bf2f(px[j]) * bf2f(f2bf(w));   // match GEMM numerics (bf16 operands)
  }
#pragma unroll
  for (int m = 1; m <= 32; m <<= 1) { dot += __shfl_xor(dot, m); nsq += __shfl_xor(nsq, m); }
  if (lane == 0) {
    const float LAMB = 1000.0f / 1.12f;   // iter=1 -> max(5, 1000/1.12)
    float rinv = 1.0f / fmaxf(sqrtf(nsq), 1e-12f);
    float c = fminf(fmaxf(dot * rinv, -1.0f), 1.0f);
    float c2 = c * c;
    float cm = 8.0f * c2 * c2 - 8.0f * c2 + 1.0f;   // cos(4θ)
    float th = acosf(c);
    float kf = floorf(4.0f * th / 3.14159265f);
    float phi = ((((int)kf) & 1) ? -cm : cm) - 2.0f * kf;
    float fr = FN[row];
    float zu = fr * c;
    float zm = fr * (c + (phi - c) / (1.0f + LAMB));
    ZT[row] = make_float2(zu, zm);
  }
}

// ------- Pass E1: combine 1340 partials per row -> per-row CE loss ----------
__global__ __launch_bounds__(256) void k_lse(const float2* __restrict__ PART,
                                             const float2* __restrict__ ZT,
                                             float* __restrict__ LOSSI) {
  int row = blockIdx.x;
  int t = threadIdx.x;
  const float NEG_INF = -__builtin_inff();
  float m = NEG_INF, ss = 0.f;
  for (int p = t; p < N_PART; p += 256) {
    float2 ps = PART[(size_t)row * N_PART + p];
    if (ps.y > 0.f) {
      if (ps.x > m) { ss = ss * __expf(m - ps.x) + ps.y; m = ps.x; }
      else          { ss += ps.y * __expf(ps.x - m); }
    }
  }
  __shared__ float sm[256], sv[256];
  sm[t] = m; sv[t] = ss;
  __syncthreads();
  for (int o = 128; o > 0; o >>= 1) {
    if (t < o) {
      float m1 = sm[t], s1 = sv[t];
      float m2 = sm[t + o], s2 = sv[t + o];
      float mm = fmaxf(m1, m2);
      float e1 = (m1 > NEG_INF) ? s1 * __expf(m1 - mm) : 0.f;
      float e2 = (m2 > NEG_INF) ? s2 * __expf(m2 - mm) : 0.f;
      sm[t] = mm; sv[t] = e1 + e2;
    }
    __syncthreads();
  }
  if (t == 0) {
    float M = sm[0], S = sv[0];
    float2 zt = ZT[row];
    // swap the target's unmodified exp term for the margin-modified one
    S += __expf(zt.y - M) - __expf(zt.x - M);
    LOSSI[row] = M + logf(S) - zt.y;
  }
}

// ------- Pass E2: mean over 512 rows -> scalar loss -------------------------
__global__ __launch_bounds__(256) void k_mean(const float* __restrict__ LOSSI,
                                              float* __restrict__ OUT) {
  int t = threadIdx.x;
  float s_ = LOSSI[t] + LOSSI[t + 256];
#pragma unroll
  for (int m = 1; m <= 32; m <<= 1) s_ += __shfl_xor(s_, m);
  __shared__ float wsum[4];
  if ((t & 63) == 0) wsum[t >> 6] = s_;
  __syncthreads();
  if (t == 0) OUT[0] = (wsum[0] + wsum[1] + wsum[2] + wsum[3]) * (1.0f / 512.0f);
}

extern "C" void kernel_launch(void* const* d_in, const int* in_sizes, int n_in,
                              void* d_out, int out_size, void* d_ws, size_t ws_size,
                              hipStream_t stream) {
  const float* X   = (const float*)d_in[0];   // [512,512] f32
  const float* W   = (const float*)d_in[1];   // [85742,512] f32
  const int*   LBL = (const int*)d_in[2];     // [512] i32
  float* OUT = (float*)d_out;

  char* ws = (char*)d_ws;
  unsigned short* XN = (unsigned short*)ws;            // 512*512*2       = 524288
  float*  FN    = (float*)(ws + 524288);               // 512*4           = 2048
  float2* ZT    = (float2*)(ws + 526336);              // 512*8           = 4096
  float*  LOSSI = (float*)(ws + 530432);               // 512*4           = 2048
  float2* PART  = (float2*)(ws + 532480);              // 512*1340*8      = 5488640

  k_xnorm  <<<dim3(128),  dim3(256), 0, stream>>>(X, XN, FN);
  k_gemm_lse<<<dim3(2680), dim3(512), 0, stream>>>(W, XN, FN, PART);
  k_target <<<dim3(512),  dim3(64),  0, stream>>>(W, XN, FN, LBL, ZT);
  k_lse    <<<dim3(512),  dim3(256), 0, stream>>>(PART, ZT, LOSSI);
  k_mean   <<<dim3(1),    dim3(256), 0, stream>>>(LOSSI, OUT);
}

// Round 4
// 122.225 us; speedup vs baseline: 2.3552x; 2.3552x over previous
//
#include <hip/hip_runtime.h>
#include <stdint.h>

#define D_K 512
#define C_CLS 85742
#define N_TILES 670            // ceil(85742/128)
#define N_PART (N_TILES * 2)

using bf16x8 = __attribute__((ext_vector_type(8))) short;
using f32x4  = __attribute__((ext_vector_type(4))) float;

__device__ __forceinline__ unsigned short f2bf(float f) {
  unsigned int u = __builtin_bit_cast(unsigned int, f);
  u += 0x7FFFu + ((u >> 16) & 1u);          // round-to-nearest-even
  return (unsigned short)(u >> 16);
}
__device__ __forceinline__ float bf2f(unsigned short h) {
  return __builtin_bit_cast(float, ((unsigned int)h) << 16);
}
__device__ __forceinline__ float sq8(const float4& a, const float4& b) {
  return a.x*a.x + a.y*a.y + a.z*a.z + a.w*a.w +
         b.x*b.x + b.y*b.y + b.z*b.z + b.w*b.w;
}
__device__ __forceinline__ void pack8(const float4& a, const float4& b, unsigned short* h) {
  h[0]=f2bf(a.x); h[1]=f2bf(a.y); h[2]=f2bf(a.z); h[3]=f2bf(a.w);
  h[4]=f2bf(b.x); h[5]=f2bf(b.y); h[6]=f2bf(b.z); h[7]=f2bf(b.w);
}

// ---------------- Pass A: normalize x -> bf16 xn, save ||x|| ----------------
__global__ __launch_bounds__(256) void k_xnorm(const float* __restrict__ X,
                                               unsigned short* __restrict__ XN,
                                               float* __restrict__ FN) {
  int row  = blockIdx.x * 4 + (threadIdx.x >> 6);
  int lane = threadIdx.x & 63;
  const float4* px = (const float4*)(X + (size_t)row * D_K + lane * 8);
  float4 u = px[0], v = px[1];
  float nsq = sq8(u, v);
#pragma unroll
  for (int m = 1; m <= 32; m <<= 1) nsq += __shfl_xor(nsq, m);
  float nrm = sqrtf(nsq);
  float inv = 1.0f / fmaxf(nrm, 1e-12f);
  float4 a = make_float4(u.x*inv, u.y*inv, u.z*inv, u.w*inv);
  float4 b = make_float4(v.x*inv, v.y*inv, v.z*inv, v.w*inv);
  alignas(16) unsigned short h[8];
  pack8(a, b, h);
  *(bf16x8*)(XN + (size_t)row * D_K + lane * 8) = *(const bf16x8*)h;
  if (lane == 0) FN[row] = nrm;
}

// ---- Pass C: 128x128 bf16 MFMA GEMM. Round-1 layout (256 thr, 4 waves,
// ---- wave-tile 64x64, BK=32, linear LDS) + double-buffered LDS with ONE
// ---- barrier per K-step: STAGE(kt+1) issued BEFORE the MFMA phase of kt,
// ---- CONV_B(kt+1) after it, so the barrier's vmcnt(0) drain is covered by
// ---- the compute phase instead of exposing full load latency twice/step.
// ---- Fused per-row ||w||^2; epilogue emits per-(row,64col) (max,sumexp).
__global__ __launch_bounds__(256) void k_gemm_lse(const float* __restrict__ W,
                                                  const unsigned short* __restrict__ XN,
                                                  const float* __restrict__ FN,
                                                  float2* __restrict__ PART) {
  __shared__ alignas(16) unsigned short As[2][4096];   // [buf][128 rows x 32 cols]
  __shared__ alignas(16) unsigned short Bs[2][4096];
  __shared__ float nsqS[128];
  __shared__ float fnS[128];

  int bid = blockIdx.x;
  // bijective XCD chunking: 2680 = 8*335; 4 m-blocks of an n-tile stay on one XCD
  int wg    = (bid & 7) * 335 + (bid >> 3);
  int ntile = wg >> 2, mtile = wg & 3;
  int m0 = mtile * 128, n0 = ntile * 128;

  int t    = threadIdx.x;
  int lane = t & 63, wid = t >> 6;
  int wm = wid >> 1, wn = wid & 1;
  int s = lane & 15, g = lane >> 4;

  // B staging: thread t owns rows r1=t>>2 and 64+r1, cols (t&3)*8..+7.
  // OOB rows clamp to the last row (uniform, branch-free); epilogue masks them.
  int r1 = t >> 2;
  int c0 = (t & 3) * 8;
  int gr1 = n0 + r1;      if (gr1 > C_CLS - 1) gr1 = C_CLS - 1;
  int gr2 = n0 + 64 + r1; if (gr2 > C_CLS - 1) gr2 = C_CLS - 1;
  const float* pB1 = W + (size_t)gr1 * D_K + c0;
  const float* pB2 = W + (size_t)gr2 * D_K + c0;

  // A staging via global_load_lds(16B): linear dest = wave base + lane*16
  const unsigned short* gA0 = XN + (size_t)(m0 + wid * 16 + (lane >> 2)) * D_K + (lane & 3) * 8;
  f32x4 acc[4][4] = {};
  float nsq1 = 0.f, nsq2 = 0.f;
  float4 ra0, ra1, rb0, rb1;

#define GLDS(srcp, dstp) __builtin_amdgcn_global_load_lds( \
    (const __attribute__((address_space(1))) unsigned int*)(srcp), \
    (__attribute__((address_space(3))) unsigned int*)(dstp), 16, 0, 0)

#define STAGE_A(b, kk) do { \
    GLDS(gA0 + (size_t)(kk) * 32,            &As[b][wid * 512]); \
    GLDS(gA0 + 64 * D_K + (size_t)(kk) * 32, &As[b][2048 + wid * 512]); \
  } while (0)

#define PREF_B(kk) do { \
    const float* q1_ = pB1 + (size_t)(kk) * 32; \
    const float* q2_ = pB2 + (size_t)(kk) * 32; \
    ra0 = *(const float4*)q1_; ra1 = *(const float4*)(q1_ + 4); \
    rb0 = *(const float4*)q2_; rb1 = *(const float4*)(q2_ + 4); \
  } while (0)

#define CONV_B(b) do { \
    nsq1 += sq8(ra0, ra1); \
    nsq2 += sq8(rb0, rb1); \
    alignas(16) unsigned short h1_[8], h2_[8]; \
    pack8(ra0, ra1, h1_); pack8(rb0, rb1, h2_); \
    *(bf16x8*)(&Bs[b][t * 8])        = *(const bf16x8*)h1_; \
    *(bf16x8*)(&Bs[b][2048 + t * 8]) = *(const bf16x8*)h2_; \
  } while (0)

#define FRAGS_MFMA(b) do { \
    bf16x8 af[4], bfr[4]; \
    _Pragma("unroll") for (int mf = 0; mf < 4; ++mf) \
      af[mf] = *(const bf16x8*)(&As[b][(wm * 64 + mf * 16 + s) * 32 + g * 8]); \
    _Pragma("unroll") for (int nf = 0; nf < 4; ++nf) \
      bfr[nf] = *(const bf16x8*)(&Bs[b][(wn * 64 + nf * 16 + s) * 32 + g * 8]); \
    _Pragma("unroll") for (int mf = 0; mf < 4; ++mf) \
      _Pragma("unroll") for (int nf = 0; nf < 4; ++nf) \
        acc[mf][nf] = __builtin_amdgcn_mfma_f32_16x16x32_bf16(af[mf], bfr[nf], acc[mf][nf], 0, 0, 0); \
  } while (0)

  // ---- prologue: tile 0 into buf0 ----
  STAGE_A(0, 0);
  PREF_B(0);
  if (t < 128) fnS[t] = FN[m0 + t];
  CONV_B(0);                    // waits B(0) regs; glds(0) older -> also done
  __syncthreads();              // buf0 fully visible

  // ---- main loop: 16 K-steps, ONE barrier each ----
  for (int kt = 0; kt < 16; ++kt) {
    int cur = kt & 1;
    if (kt < 15) {
      STAGE_A(cur ^ 1, kt + 1); // async glds into other buffer
      PREF_B(kt + 1);           // B regs for next tile
    }
    FRAGS_MFMA(cur);            // ds_read + 16 MFMA cover the loads above
    if (kt < 15) {
      CONV_B(cur ^ 1);          // pack B(kt+1) -> other buffer
      __syncthreads();          // drains glds (covered); publishes buffers
    }
  }

  // finish per-row ||w||^2: combine the 4 col-chunk owners (t^1, t^2)
  nsq1 += __shfl_xor(nsq1, 1); nsq1 += __shfl_xor(nsq1, 2);
  nsq2 += __shfl_xor(nsq2, 1); nsq2 += __shfl_xor(nsq2, 2);
  if ((t & 3) == 0) { nsqS[r1] = nsq1; nsqS[64 + r1] = nsq2; }
  __syncthreads();

  float rinv[4]; int cvalid[4];
#pragma unroll
  for (int nf = 0; nf < 4; ++nf) {
    int cl = wn * 64 + nf * 16 + s;
    cvalid[nf] = (n0 + cl) < C_CLS;
    rinv[nf] = 1.0f / fmaxf(sqrtf(nsqS[cl]), 1e-12f);
  }
  const float NEG_INF = -__builtin_inff();
#pragma unroll
  for (int mf = 0; mf < 4; ++mf) {
#pragma unroll
    for (int q = 0; q < 4; ++q) {
      int rl = wm * 64 + mf * 16 + g * 4 + q;     // D row = (lane>>4)*4+reg
      float fr = fnS[rl];
      float z[4]; float mx = NEG_INF;
#pragma unroll
      for (int nf = 0; nf < 4; ++nf) {
        float cc = acc[mf][nf][q] * rinv[nf];
        cc = fminf(fmaxf(cc, -1.0f), 1.0f);
        z[nf] = cvalid[nf] ? cc * fr : NEG_INF;
        mx = fmaxf(mx, z[nf]);
      }
#pragma unroll
      for (int d = 1; d <= 8; d <<= 1) mx = fmaxf(mx, __shfl_xor(mx, d));
      float se = 0.f;
#pragma unroll
      for (int nf = 0; nf < 4; ++nf) se += __expf(z[nf] - mx);  // exp(-inf)=0
#pragma unroll
      for (int d = 1; d <= 8; d <<= 1) se += __shfl_xor(se, d);
      if (s == mf * 4 + q)
        PART[(size_t)(m0 + rl) * N_PART + (ntile * 2 + wn)] = make_float2(mx, se);
    }
  }
}

// ------- Pass D: per-row target logit (unmodified + margin-modified) --------
__global__ __launch_bounds__(64) void k_target(const float* __restrict__ W,
                                               const unsigned short* __restrict__ XN,
                                               const float* __restrict__ FN,
                                               const int* __restrict__ LBL,
                                               float2* __restrict__ ZT) {
  int row = blockIdx.x;
  int lane = threadIdx.x;
  int lab = LBL[row];
  const float* pw = W + (size_t)lab * D_K + lane * 8;
  const unsigned short* px = XN + (size_t)row * D_K + lane * 8;
  float dot = 0.f, nsq = 0.f;
#pragma unroll
  for (int j = 0; j < 8; ++j) {
    float w = pw[j];
    nsq += w * w;
    dot += bf2f(px[j]) * bf2f(f2bf(w));   // match GEMM numerics (bf16 operands)
  }
#pragma unroll
  for (int m = 1; m <= 32; m <<= 1) { dot += __shfl_xor(dot, m); nsq += __shfl_xor(nsq, m); }
  if (lane == 0) {
    const float LAMB = 1000.0f / 1.12f;   // iter=1 -> max(5, 1000/1.12)
    float rinv = 1.0f / fmaxf(sqrtf(nsq), 1e-12f);
    float c = fminf(fmaxf(dot * rinv, -1.0f), 1.0f);
    float c2 = c * c;
    float cm = 8.0f * c2 * c2 - 8.0f * c2 + 1.0f;   // cos(4θ)
    float th = acosf(c);
    float kf = floorf(4.0f * th / 3.14159265f);
    float phi = ((((int)kf) & 1) ? -cm : cm) - 2.0f * kf;
    float fr = FN[row];
    float zu = fr * c;
    float zm = fr * (c + (phi - c) / (1.0f + LAMB));
    ZT[row] = make_float2(zu, zm);
  }
}

// ------- Pass E1: combine 1340 partials per row -> per-row CE loss ----------
__global__ __launch_bounds__(256) void k_lse(const float2* __restrict__ PART,
                                             const float2* __restrict__ ZT,
                                             float* __restrict__ LOSSI) {
  int row = blockIdx.x;
  int t = threadIdx.x;
  const float NEG_INF = -__builtin_inff();
  float m = NEG_INF, ss = 0.f;
  for (int p = t; p < N_PART; p += 256) {
    float2 ps = PART[(size_t)row * N_PART + p];
    if (ps.y > 0.f) {
      if (ps.x > m) { ss = ss * __expf(m - ps.x) + ps.y; m = ps.x; }
      else          { ss += ps.y * __expf(ps.x - m); }
    }
  }
  __shared__ float sm[256], sv[256];
  sm[t] = m; sv[t] = ss;
  __syncthreads();
  for (int o = 128; o > 0; o >>= 1) {
    if (t < o) {
      float m1 = sm[t], s1 = sv[t];
      float m2 = sm[t + o], s2 = sv[t + o];
      float mm = fmaxf(m1, m2);
      float e1 = (m1 > NEG_INF) ? s1 * __expf(m1 - mm) : 0.f;
      float e2 = (m2 > NEG_INF) ? s2 * __expf(m2 - mm) : 0.f;
      sm[t] = mm; sv[t] = e1 + e2;
    }
    __syncthreads();
  }
  if (t == 0) {
    float M = sm[0], S = sv[0];
    float2 zt = ZT[row];
    // swap the target's unmodified exp term for the margin-modified one
    S += __expf(zt.y - M) - __expf(zt.x - M);
    LOSSI[row] = M + logf(S) - zt.y;
  }
}

// ------- Pass E2: mean over 512 rows -> scalar loss -------------------------
__global__ __launch_bounds__(256) void k_mean(const float* __restrict__ LOSSI,
                                              float* __restrict__ OUT) {
  int t = threadIdx.x;
  float s_ = LOSSI[t] + LOSSI[t + 256];
#pragma unroll
  for (int m = 1; m <= 32; m <<= 1) s_ += __shfl_xor(s_, m);
  __shared__ float wsum[4];
  if ((t & 63) == 0) wsum[t >> 6] = s_;
  __syncthreads();
  if (t == 0) OUT[0] = (wsum[0] + wsum[1] + wsum[2] + wsum[3]) * (1.0f / 512.0f);
}

extern "C" void kernel_launch(void* const* d_in, const int* in_sizes, int n_in,
                              void* d_out, int out_size, void* d_ws, size_t ws_size,
                              hipStream_t stream) {
  const float* X   = (const float*)d_in[0];   // [512,512] f32
  const float* W   = (const float*)d_in[1];   // [85742,512] f32
  const int*   LBL = (const int*)d_in[2];     // [512] i32
  float* OUT = (float*)d_out;

  char* ws = (char*)d_ws;
  unsigned short* XN = (unsigned short*)ws;            // 512*512*2       = 524288
  float*  FN    = (float*)(ws + 524288);               // 512*4           = 2048
  float2* ZT    = (float2*)(ws + 526336);              // 512*8           = 4096
  float*  LOSSI = (float*)(ws + 530432);               // 512*4           = 2048
  float2* PART  = (float2*)(ws + 532480);              // 512*1340*8      = 5488640

  k_xnorm  <<<dim3(128),  dim3(256), 0, stream>>>(X, XN, FN);
  k_gemm_lse<<<dim3(2680), dim3(256), 0, stream>>>(W, XN, FN, PART);
  k_target <<<dim3(512),  dim3(64),  0, stream>>>(W, XN, FN, LBL, ZT);
  k_lse    <<<dim3(512),  dim3(256), 0, stream>>>(PART, ZT, LOSSI);
  k_mean   <<<dim3(1),    dim3(256), 0, stream>>>(LOSSI, OUT);
}

// Round 5
// 112.594 us; speedup vs baseline: 2.5566x; 1.0855x over previous
//
#include <hip/hip_runtime.h>
#include <stdint.h>

#define D_K 512
#define C_CLS 85742
#define N_TILES 670            // ceil(85742/128)
#define N_PART (N_TILES * 2)

using bf16x8 = __attribute__((ext_vector_type(8))) short;
using f32x4  = __attribute__((ext_vector_type(4))) float;

// v_cvt_pk_bf16_f32: dst = {lo: bf16(a), hi: bf16(b)}, RNE. No builtin on
// gfx950 (m240) -> inline asm, non-volatile so the scheduler can move it.
__device__ __forceinline__ unsigned int cvtpk(float a, float b) {
  unsigned int r;
  asm("v_cvt_pk_bf16_f32 %0, %1, %2" : "=v"(r) : "v"(a), "v"(b));
  return r;
}
__device__ __forceinline__ unsigned short f2bf(float f) {
  unsigned int u = __builtin_bit_cast(unsigned int, f);
  u += 0x7FFFu + ((u >> 16) & 1u);          // round-to-nearest-even
  return (unsigned short)(u >> 16);
}
__device__ __forceinline__ float bf2f(unsigned short h) {
  return __builtin_bit_cast(float, ((unsigned int)h) << 16);
}
__device__ __forceinline__ float sq8(const float4& a, const float4& b) {
  return a.x*a.x + a.y*a.y + a.z*a.z + a.w*a.w +
         b.x*b.x + b.y*b.y + b.z*b.z + b.w*b.w;
}

// ---------------- Pass A: normalize x -> bf16 xn, save ||x|| ----------------
__global__ __launch_bounds__(256) void k_xnorm(const float* __restrict__ X,
                                               unsigned short* __restrict__ XN,
                                               float* __restrict__ FN) {
  int row  = blockIdx.x * 4 + (threadIdx.x >> 6);
  int lane = threadIdx.x & 63;
  const float4* px = (const float4*)(X + (size_t)row * D_K + lane * 8);
  float4 u = px[0], v = px[1];
  float nsq = sq8(u, v);
#pragma unroll
  for (int m = 1; m <= 32; m <<= 1) nsq += __shfl_xor(nsq, m);
  float nrm = sqrtf(nsq);
  float inv = 1.0f / fmaxf(nrm, 1e-12f);
  uint4 o;
  o.x = cvtpk(u.x*inv, u.y*inv); o.y = cvtpk(u.z*inv, u.w*inv);
  o.z = cvtpk(v.x*inv, v.y*inv); o.w = cvtpk(v.z*inv, v.w*inv);
  *(uint4*)(XN + (size_t)row * D_K + lane * 8) = o;
  if (lane == 0) FN[row] = nrm;
}

// ---- Pass C: 128x128 bf16 MFMA GEMM (256 thr, 4 waves, wave-tile 64x64,
// ---- BK=32, dbuf LDS, one barrier/K-step). B = raw W fp32 reg-staged ->
// ---- bf16 LDS via v_cvt_pk_bf16_f32 (8 instrs/16 elems, vs ~64 manual);
// ---- fused per-row ||w||^2. A = xn bf16 via global_load_lds. Epilogue:
// ---- per-(row,64col) (max,sumexp) partials of z = clamp(cos)*||x||.
__global__ __launch_bounds__(256) void k_gemm_lse(const float* __restrict__ W,
                                                  const unsigned short* __restrict__ XN,
                                                  const float* __restrict__ FN,
                                                  float2* __restrict__ PART) {
  __shared__ alignas(16) unsigned short As[2][4096];   // [buf][128 rows x 32 cols]
  __shared__ alignas(16) unsigned short Bs[2][4096];
  __shared__ float nsqS[128];
  __shared__ float fnS[128];

  int bid = blockIdx.x;
  // bijective XCD chunking: 2680 = 8*335; 4 m-blocks of an n-tile stay on one XCD
  int wg    = (bid & 7) * 335 + (bid >> 3);
  int ntile = wg >> 2, mtile = wg & 3;
  int m0 = mtile * 128, n0 = ntile * 128;

  int t    = threadIdx.x;
  int lane = t & 63, wid = t >> 6;
  int wm = wid >> 1, wn = wid & 1;
  int s = lane & 15, g = lane >> 4;

  // B staging: thread t owns rows r1=t>>2 and 64+r1, cols (t&3)*8..+7.
  // OOB rows clamp to the last row (uniform, branch-free); epilogue masks them.
  int r1 = t >> 2;
  int c0 = (t & 3) * 8;
  int gr1 = n0 + r1;      if (gr1 > C_CLS - 1) gr1 = C_CLS - 1;
  int gr2 = n0 + 64 + r1; if (gr2 > C_CLS - 1) gr2 = C_CLS - 1;
  const float* pB1 = W + (size_t)gr1 * D_K + c0;
  const float* pB2 = W + (size_t)gr2 * D_K + c0;

  // A staging via global_load_lds(16B): linear dest = wave base + lane*16
  const unsigned short* gA0 = XN + (size_t)(m0 + wid * 16 + (lane >> 2)) * D_K + (lane & 3) * 8;
  f32x4 acc[4][4] = {};
  float nsq1 = 0.f, nsq2 = 0.f;
  float4 ra0, ra1, rb0, rb1;

#define GLDS(srcp, dstp) __builtin_amdgcn_global_load_lds( \
    (const __attribute__((address_space(1))) unsigned int*)(srcp), \
    (__attribute__((address_space(3))) unsigned int*)(dstp), 16, 0, 0)

#define STAGE_A(b, kk) do { \
    GLDS(gA0 + (size_t)(kk) * 32,            &As[b][wid * 512]); \
    GLDS(gA0 + 64 * D_K + (size_t)(kk) * 32, &As[b][2048 + wid * 512]); \
  } while (0)

#define PREF_B(kk) do { \
    const float* q1_ = pB1 + (size_t)(kk) * 32; \
    const float* q2_ = pB2 + (size_t)(kk) * 32; \
    ra0 = *(const float4*)q1_; ra1 = *(const float4*)(q1_ + 4); \
    rb0 = *(const float4*)q2_; rb1 = *(const float4*)(q2_ + 4); \
  } while (0)

#define CONV_B(b) do { \
    nsq1 += sq8(ra0, ra1); \
    nsq2 += sq8(rb0, rb1); \
    uint4 u1_, u2_; \
    u1_.x = cvtpk(ra0.x, ra0.y); u1_.y = cvtpk(ra0.z, ra0.w); \
    u1_.z = cvtpk(ra1.x, ra1.y); u1_.w = cvtpk(ra1.z, ra1.w); \
    u2_.x = cvtpk(rb0.x, rb0.y); u2_.y = cvtpk(rb0.z, rb0.w); \
    u2_.z = cvtpk(rb1.x, rb1.y); u2_.w = cvtpk(rb1.z, rb1.w); \
    *(uint4*)(&Bs[b][t * 8])        = u1_; \
    *(uint4*)(&Bs[b][2048 + t * 8]) = u2_; \
  } while (0)

#define FRAGS_MFMA(b) do { \
    bf16x8 af[4], bfr[4]; \
    _Pragma("unroll") for (int mf = 0; mf < 4; ++mf) \
      af[mf] = *(const bf16x8*)(&As[b][(wm * 64 + mf * 16 + s) * 32 + g * 8]); \
    _Pragma("unroll") for (int nf = 0; nf < 4; ++nf) \
      bfr[nf] = *(const bf16x8*)(&Bs[b][(wn * 64 + nf * 16 + s) * 32 + g * 8]); \
    _Pragma("unroll") for (int mf = 0; mf < 4; ++mf) \
      _Pragma("unroll") for (int nf = 0; nf < 4; ++nf) \
        acc[mf][nf] = __builtin_amdgcn_mfma_f32_16x16x32_bf16(af[mf], bfr[nf], acc[mf][nf], 0, 0, 0); \
  } while (0)

  // ---- prologue: tile 0 into buf0 ----
  STAGE_A(0, 0);
  PREF_B(0);
  if (t < 128) fnS[t] = FN[m0 + t];
  CONV_B(0);                    // waits B(0) regs; glds(0) older -> also done
  __syncthreads();              // buf0 fully visible

  // ---- main loop: 15 full K-steps + peeled tail, ONE barrier each ----
  for (int kt = 0; kt < 15; ++kt) {
    int cur = kt & 1;
    STAGE_A(cur ^ 1, kt + 1);   // async glds into other buffer
    PREF_B(kt + 1);             // B regs for next tile
    FRAGS_MFMA(cur);            // ds_read + 16 MFMA cover the loads above
    CONV_B(cur ^ 1);            // pack B(kt+1) -> other buffer
    __syncthreads();            // drains glds (covered); publishes buffers
  }
  FRAGS_MFMA(1);                // kt = 15

  // finish per-row ||w||^2: combine the 4 col-chunk owners (t^1, t^2)
  nsq1 += __shfl_xor(nsq1, 1); nsq1 += __shfl_xor(nsq1, 2);
  nsq2 += __shfl_xor(nsq2, 1); nsq2 += __shfl_xor(nsq2, 2);
  if ((t & 3) == 0) { nsqS[r1] = nsq1; nsqS[64 + r1] = nsq2; }
  __syncthreads();

  float rinv[4]; int cvalid[4];
#pragma unroll
  for (int nf = 0; nf < 4; ++nf) {
    int cl = wn * 64 + nf * 16 + s;
    cvalid[nf] = (n0 + cl) < C_CLS;
    rinv[nf] = 1.0f / fmaxf(sqrtf(nsqS[cl]), 1e-12f);
  }
  const float NEG_INF = -__builtin_inff();
#pragma unroll
  for (int mf = 0; mf < 4; ++mf) {
#pragma unroll
    for (int q = 0; q < 4; ++q) {
      int rl = wm * 64 + mf * 16 + g * 4 + q;     // D row = (lane>>4)*4+reg
      float fr = fnS[rl];
      float z[4]; float mx = NEG_INF;
#pragma unroll
      for (int nf = 0; nf < 4; ++nf) {
        float cc = acc[mf][nf][q] * rinv[nf];
        cc = fminf(fmaxf(cc, -1.0f), 1.0f);
        z[nf] = cvalid[nf] ? cc * fr : NEG_INF;
        mx = fmaxf(mx, z[nf]);
      }
#pragma unroll
      for (int d = 1; d <= 8; d <<= 1) mx = fmaxf(mx, __shfl_xor(mx, d));
      float se = 0.f;
#pragma unroll
      for (int nf = 0; nf < 4; ++nf) se += __expf(z[nf] - mx);  // exp(-inf)=0
#pragma unroll
      for (int d = 1; d <= 8; d <<= 1) se += __shfl_xor(se, d);
      if (s == mf * 4 + q)
        PART[(size_t)(m0 + rl) * N_PART + (ntile * 2 + wn)] = make_float2(mx, se);
    }
  }
}

// ------- Pass D: per-row target logit (unmodified + margin-modified) --------
__global__ __launch_bounds__(64) void k_target(const float* __restrict__ W,
                                               const unsigned short* __restrict__ XN,
                                               const float* __restrict__ FN,
                                               const int* __restrict__ LBL,
                                               float2* __restrict__ ZT) {
  int row = blockIdx.x;
  int lane = threadIdx.x;
  int lab = LBL[row];
  const float* pw = W + (size_t)lab * D_K + lane * 8;
  const unsigned short* px = XN + (size_t)row * D_K + lane * 8;
  float dot = 0.f, nsq = 0.f;
#pragma unroll
  for (int j = 0; j < 8; ++j) {
    float w = pw[j];
    nsq += w * w;
    dot += bf2f(px[j]) * bf2f(f2bf(w));   // match GEMM numerics (bf16 operands)
  }
#pragma unroll
  for (int m = 1; m <= 32; m <<= 1) { dot += __shfl_xor(dot, m); nsq += __shfl_xor(nsq, m); }
  if (lane == 0) {
    const float LAMB = 1000.0f / 1.12f;   // iter=1 -> max(5, 1000/1.12)
    float rinv = 1.0f / fmaxf(sqrtf(nsq), 1e-12f);
    float c = fminf(fmaxf(dot * rinv, -1.0f), 1.0f);
    float c2 = c * c;
    float cm = 8.0f * c2 * c2 - 8.0f * c2 + 1.0f;   // cos(4θ)
    float th = acosf(c);
    float kf = floorf(4.0f * th / 3.14159265f);
    float phi = ((((int)kf) & 1) ? -cm : cm) - 2.0f * kf;
    float fr = FN[row];
    float zu = fr * c;
    float zm = fr * (c + (phi - c) / (1.0f + LAMB));
    ZT[row] = make_float2(zu, zm);
  }
}

// ------- Pass E1: combine 1340 partials per row -> per-row CE loss ----------
__global__ __launch_bounds__(256) void k_lse(const float2* __restrict__ PART,
                                             const float2* __restrict__ ZT,
                                             float* __restrict__ LOSSI) {
  int row = blockIdx.x;
  int t = threadIdx.x;
  const float NEG_INF = -__builtin_inff();
  float m = NEG_INF, ss = 0.f;
  for (int p = t; p < N_PART; p += 256) {
    float2 ps = PART[(size_t)row * N_PART + p];
    if (ps.y > 0.f) {
      if (ps.x > m) { ss = ss * __expf(m - ps.x) + ps.y; m = ps.x; }
      else          { ss += ps.y * __expf(ps.x - m); }
    }
  }
  __shared__ float sm[256], sv[256];
  sm[t] = m; sv[t] = ss;
  __syncthreads();
  for (int o = 128; o > 0; o >>= 1) {
    if (t < o) {
      float m1 = sm[t], s1 = sv[t];
      float m2 = sm[t + o], s2 = sv[t + o];
      float mm = fmaxf(m1, m2);
      float e1 = (m1 > NEG_INF) ? s1 * __expf(m1 - mm) : 0.f;
      float e2 = (m2 > NEG_INF) ? s2 * __expf(m2 - mm) : 0.f;
      sm[t] = mm; sv[t] = e1 + e2;
    }
    __syncthreads();
  }
  if (t == 0) {
    float M = sm[0], S = sv[0];
    float2 zt = ZT[row];
    // swap the target's unmodified exp term for the margin-modified one
    S += __expf(zt.y - M) - __expf(zt.x - M);
    LOSSI[row] = M + logf(S) - zt.y;
  }
}

// ------- Pass E2: mean over 512 rows -> scalar loss -------------------------
__global__ __launch_bounds__(256) void k_mean(const float* __restrict__ LOSSI,
                                              float* __restrict__ OUT) {
  int t = threadIdx.x;
  float s_ = LOSSI[t] + LOSSI[t + 256];
#pragma unroll
  for (int m = 1; m <= 32; m <<= 1) s_ += __shfl_xor(s_, m);
  __shared__ float wsum[4];
  if ((t & 63) == 0) wsum[t >> 6] = s_;
  __syncthreads();
  if (t == 0) OUT[0] = (wsum[0] + wsum[1] + wsum[2] + wsum[3]) * (1.0f / 512.0f);
}

extern "C" void kernel_launch(void* const* d_in, const int* in_sizes, int n_in,
                              void* d_out, int out_size, void* d_ws, size_t ws_size,
                              hipStream_t stream) {
  const float* X   = (const float*)d_in[0];   // [512,512] f32
  const float* W   = (const float*)d_in[1];   // [85742,512] f32
  const int*   LBL = (const int*)d_in[2];     // [512] i32
  float* OUT = (float*)d_out;

  char* ws = (char*)d_ws;
  unsigned short* XN = (unsigned short*)ws;            // 512*512*2       = 524288
  float*  FN    = (float*)(ws + 524288);               // 512*4           = 2048
  float2* ZT    = (float2*)(ws + 526336);              // 512*8           = 4096
  float*  LOSSI = (float*)(ws + 530432);               // 512*4           = 2048
  float2* PART  = (float2*)(ws + 532480);              // 512*1340*8      = 5488640

  k_xnorm  <<<dim3(128),  dim3(256), 0, stream>>>(X, XN, FN);
  k_gemm_lse<<<dim3(2680), dim3(256), 0, stream>>>(W, XN, FN, PART);
  k_target <<<dim3(512),  dim3(64),  0, stream>>>(W, XN, FN, LBL, ZT);
  k_lse    <<<dim3(512),  dim3(256), 0, stream>>>(PART, ZT, LOSSI);
  k_mean   <<<dim3(1),    dim3(256), 0, stream>>>(LOSSI, OUT);
}